// Round 6
// baseline (189.398 us; speedup 1.0000x reference)
//
#include <hip/hip_runtime.h>
#include <hip/hip_bf16.h>
#include <math.h>
#include <stdint.h>

// Problem constants (reference: BATCH=8, T=2048, N=512)
#define BATCH 8
#define T_LEN 2048
#define NDIM 512
#define M_ROWS (BATCH * T_LEN)   // 16384
#define CHUNK 32                 // scan chunk length
#define NCHUNK (T_LEN / CHUNK)   // 64

typedef __attribute__((ext_vector_type(8))) short bf16x8;
typedef __attribute__((ext_vector_type(16))) float floatx16;

__device__ __forceinline__ unsigned short f2bf(float f) {
    union { float f; unsigned u; } v; v.f = f;
    unsigned r = v.u + 0x7fff + ((v.u >> 16) & 1);   // RTNE
    return (unsigned short)(r >> 16);
}
__device__ __forceinline__ float bf2f(unsigned short h) {
    union { unsigned u; float f; } v; v.u = ((unsigned)h) << 16;
    return v.f;
}
__device__ __forceinline__ float bf2f_lo(unsigned u) {
    union { unsigned u; float f; } v; v.u = u << 16; return v.f;
}
__device__ __forceinline__ float bf2f_hi(unsigned u) {
    union { unsigned u; float f; } v; v.u = u & 0xffff0000u; return v.f;
}

// async global->LDS, 16 bytes per lane. LDS dest is wave-uniform base + lane*16
// (lane-order contiguous) — hence BK=32 k-contiguous rows, no padding.
__device__ __forceinline__ void gld_lds16(const unsigned short* g, unsigned short* l) {
    __builtin_amdgcn_global_load_lds(
        (const __attribute__((address_space(1))) unsigned int*)(uintptr_t)g,
        (__attribute__((address_space(3))) unsigned int*)(uintptr_t)l,
        16, 0, 0);
}

// ---------------- prep (merged): u->bf16  +  transpose/convert B,C ----------
// blocks [0,4096): cvt_u flat; blocks [4096,5120): transpose tiles.
__global__ __launch_bounds__(256) void k_prep(
    const float* __restrict__ u,
    const float* __restrict__ Bre, const float* __restrict__ Bim,
    const float* __restrict__ Cre, const float* __restrict__ Cim,
    const float* __restrict__ gamma,
    unsigned short* __restrict__ ubf,
    unsigned short* __restrict__ BT, unsigned short* __restrict__ CT)
{
    __shared__ unsigned short tile[32][33];
    const int blk = blockIdx.x;
    if (blk < 4096) {
        size_t i = ((size_t)blk * 256 + threadIdx.x) * 8;
        float4 a = *(const float4*)&u[i];
        float4 b = *(const float4*)&u[i + 4];
        ushort4 p0, p1;
        p0.x = f2bf(a.x); p0.y = f2bf(a.y); p0.z = f2bf(a.z); p0.w = f2bf(a.w);
        p1.x = f2bf(b.x); p1.y = f2bf(b.y); p1.z = f2bf(b.z); p1.w = f2bf(b.w);
        *(ushort4*)&ubf[i] = p0;
        *(ushort4*)&ubf[i + 4] = p1;
        return;
    }
    const int p = blk - 4096;
    const int z = p >> 8;                    // 0..3
    const int rem = p & 255;
    const int n0 = (rem & 15) * 32, k0 = (rem >> 4) * 32;
    const float* __restrict__ src = (z == 0) ? Bre : (z == 1) ? Bim : (z == 2) ? Cre : Cim;
    const int tx = threadIdx.x & 31, ty = threadIdx.x >> 5;   // ty 0..7

#pragma unroll
    for (int j = 0; j < 4; ++j) {
        int k = k0 + ty + j * 8;
        float s = (z < 2) ? gamma[k] : (z == 3 ? -1.f : 1.f);
        tile[ty + j * 8][tx] = f2bf(s * src[(size_t)k * NDIM + n0 + tx]);
    }
    __syncthreads();
#pragma unroll
    for (int j = 0; j < 4; ++j) {
        int n = n0 + ty + j * 8;
        unsigned short v = tile[tx][ty + j * 8];
        if (z == 0)      BT[(size_t)n * 512 + k0 + tx] = v;
        else if (z == 1) BT[(size_t)(512 + n) * 512 + k0 + tx] = v;
        else if (z == 2) CT[(size_t)n * 1024 + k0 + tx] = v;
        else             CT[(size_t)n * 1024 + 512 + k0 + tx] = v;
    }
}

// ---------------- GEMM-in: X[16384][1024] = ubf[16384][512] @ BT^T ----------
// 128x128 tile, BK=32, global_load_lds staging, 4 waves, 2x2 of 32x32x16 MFMA.
__global__ __launch_bounds__(256) void k_gemm_in(
    const unsigned short* __restrict__ A,    // [16384][512] bf16
    const unsigned short* __restrict__ BT,   // [1024][512] bf16, n-major
    unsigned short* __restrict__ X)          // [16384][1024] bf16 out
{
    __shared__ unsigned short As[128 * 32];
    __shared__ unsigned short Bs[128 * 32];
    const int tid = threadIdx.x;
    const int w = tid >> 6, l = tid & 63;
    const int bm = blockIdx.x * 128;
    const int bn = blockIdx.y * 128;
    const int wm = (w & 1) * 64, wn = (w >> 1) * 64;
    const int lr = l & 31, lh = l >> 5;
    const int srow = w * 16 + (l >> 2);
    const int scol = (l & 3) * 8;

    floatx16 acc[2][2];
#pragma unroll
    for (int i = 0; i < 2; ++i)
#pragma unroll
        for (int j = 0; j < 2; ++j) acc[i][j] = (floatx16)0.f;

    for (int k0 = 0; k0 < 512; k0 += 32) {
        gld_lds16(&A[(size_t)(bm + srow) * 512 + k0 + scol],      &As[srow * 32 + scol]);
        gld_lds16(&A[(size_t)(bm + 64 + srow) * 512 + k0 + scol], &As[(64 + srow) * 32 + scol]);
        gld_lds16(&BT[(size_t)(bn + srow) * 512 + k0 + scol],      &Bs[srow * 32 + scol]);
        gld_lds16(&BT[(size_t)(bn + 64 + srow) * 512 + k0 + scol], &Bs[(64 + srow) * 32 + scol]);
        __syncthreads();

        // A/B frag: elem[m=lane&31][k=(lane>>5)*8+j] within each K=16 slice s
        bf16x8 af[2][2], bfr[2][2];
#pragma unroll
        for (int i = 0; i < 2; ++i)
#pragma unroll
            for (int s = 0; s < 2; ++s)
                af[i][s] = *(const bf16x8*)&As[(wm + 32 * i + lr) * 32 + s * 16 + lh * 8];
#pragma unroll
        for (int j = 0; j < 2; ++j)
#pragma unroll
            for (int s = 0; s < 2; ++s)
                bfr[j][s] = *(const bf16x8*)&Bs[(wn + 32 * j + lr) * 32 + s * 16 + lh * 8];
#pragma unroll
        for (int s = 0; s < 2; ++s)
#pragma unroll
            for (int i = 0; i < 2; ++i)
#pragma unroll
                for (int j = 0; j < 2; ++j)
                    acc[i][j] = __builtin_amdgcn_mfma_f32_32x32x16_bf16(af[i][s], bfr[j][s], acc[i][j], 0, 0, 0);
        __syncthreads();
    }

    // C/D layout (32x32): col=lane&31, row=(reg&3)+8*(reg>>2)+4*(lane>>5)
#pragma unroll
    for (int i = 0; i < 2; ++i)
#pragma unroll
        for (int j = 0; j < 2; ++j) {
            int col = bn + wn + 32 * j + lr;
#pragma unroll
            for (int g = 0; g < 4; ++g)
#pragma unroll
                for (int r = 0; r < 4; ++r) {
                    int row = bm + wm + 32 * i + r + 8 * g + 4 * lh;
                    X[(size_t)row * 1024 + col] = f2bf(acc[i][j][g * 4 + r]);
                }
        }
}

// ---------------- Scan pass A: per-chunk carries (2 channels/thread) --------
__global__ __launch_bounds__(256) void k_scan_carries(
    const unsigned short* __restrict__ X,
    const float* __restrict__ nu, const float* __restrict__ theta,
    float* __restrict__ carry)   // [b][c][n] float2 interleaved
{
    const int t2 = threadIdx.x;                 // handles n = 2*t2, 2*t2+1
    const int n0 = 2 * t2;
    const int b = blockIdx.x >> 6, c = blockIdx.x & 63;
    float r0 = __expf(-__expf(nu[n0]));
    float r1 = __expf(-__expf(nu[n0 + 1]));
    float lre0 = r0 * __cosf(theta[n0]),     lim0 = r0 * __sinf(theta[n0]);
    float lre1 = r1 * __cosf(theta[n0 + 1]), lim1 = r1 * __sinf(theta[n0 + 1]);
    size_t m = (size_t)b * T_LEN + (size_t)c * CHUNK;
    float xre0 = 0.f, xim0 = 0.f, xre1 = 0.f, xim1 = 0.f;
#pragma unroll 8
    for (int t = 0; t < CHUNK; ++t, ++m) {
        unsigned re = *(const unsigned*)&X[m * 1024 + n0];
        unsigned im = *(const unsigned*)&X[m * 1024 + 512 + n0];
        float u0 = bf2f_lo(re), u1 = bf2f_hi(re);
        float v0 = bf2f_lo(im), v1 = bf2f_hi(im);
        float a0 = lre0 * xre0 - lim0 * xim0 + u0;
        float b0 = lre0 * xim0 + lim0 * xre0 + v0;
        float a1 = lre1 * xre1 - lim1 * xim1 + u1;
        float b1 = lre1 * xim1 + lim1 * xre1 + v1;
        xre0 = a0; xim0 = b0; xre1 = a1; xim1 = b1;
    }
    size_t ci = ((size_t)b * NCHUNK + c) * NDIM + n0;
    *(float4*)&carry[ci * 2] = make_float4(xre0, xim0, xre1, xim1);
}

// ---------------- Scan pass B: chain carries across chunks ------------------
__global__ __launch_bounds__(256) void k_scan_chain(
    const float* __restrict__ carry,
    const float* __restrict__ nu, const float* __restrict__ theta,
    float* __restrict__ pre)     // exclusive prefix, float2 interleaved
{
    const int tid = blockIdx.x * blockDim.x + threadIdx.x;  // 0..4095
    const int b = tid >> 9, n = tid & (NDIM - 1);
    const float ex = __expf(nu[n]);
    const float rC = expf(-ex * (float)CHUNK);
    const float th = theta[n] * (float)CHUNK;
    const float a = rC * cosf(th);
    const float bb = rC * sinf(th);
    float Xre = 0.f, Xim = 0.f;
    for (int c = 0; c < NCHUNK; ++c) {
        size_t idx = ((size_t)b * NCHUNK + c) * NDIM + n;
        *(float2*)&pre[idx * 2] = make_float2(Xre, Xim);
        float2 cv = *(const float2*)&carry[idx * 2];
        float nre = a * Xre - bb * Xim + cv.x;
        float nim = a * Xim + bb * Xre + cv.y;
        Xre = nre; Xim = nim;
    }
}

// ---------------- Scan pass C: redo local scan from prefix, in place --------
__global__ __launch_bounds__(256) void k_scan_apply(
    unsigned short* __restrict__ X,
    const float* __restrict__ nu, const float* __restrict__ theta,
    const float* __restrict__ pre)
{
    const int t2 = threadIdx.x;
    const int n0 = 2 * t2;
    const int b = blockIdx.x >> 6, c = blockIdx.x & 63;
    size_t pi = ((size_t)b * NCHUNK + c) * NDIM + n0;
    float4 P = *(const float4*)&pre[pi * 2];    // (re0, im0, re1, im1)
    float r0 = __expf(-__expf(nu[n0]));
    float r1 = __expf(-__expf(nu[n0 + 1]));
    float lre0 = r0 * __cosf(theta[n0]),     lim0 = r0 * __sinf(theta[n0]);
    float lre1 = r1 * __cosf(theta[n0 + 1]), lim1 = r1 * __sinf(theta[n0 + 1]);
    float xre0 = P.x, xim0 = P.y, xre1 = P.z, xim1 = P.w;
    size_t m = (size_t)b * T_LEN + (size_t)c * CHUNK;
#pragma unroll 8
    for (int t = 0; t < CHUNK; ++t, ++m) {
        unsigned re = *(const unsigned*)&X[m * 1024 + n0];
        unsigned im = *(const unsigned*)&X[m * 1024 + 512 + n0];
        float u0 = bf2f_lo(re), u1 = bf2f_hi(re);
        float v0 = bf2f_lo(im), v1 = bf2f_hi(im);
        float a0 = lre0 * xre0 - lim0 * xim0 + u0;
        float b0 = lre0 * xim0 + lim0 * xre0 + v0;
        float a1 = lre1 * xre1 - lim1 * xim1 + u1;
        float b1 = lre1 * xim1 + lim1 * xre1 + v1;
        xre0 = a0; xim0 = b0; xre1 = a1; xim1 = b1;
        unsigned pr = (unsigned)f2bf(xre0) | ((unsigned)f2bf(xre1) << 16);
        unsigned pim = (unsigned)f2bf(xim0) | ((unsigned)f2bf(xim1) << 16);
        *(unsigned*)&X[m * 1024 + n0] = pr;
        *(unsigned*)&X[m * 1024 + 512 + n0] = pim;
    }
}

// ---------------- GEMM-out: Y = X[16384][1024] @ CT^T + D*u -----------------
__global__ __launch_bounds__(256) void k_gemm_out(
    const unsigned short* __restrict__ Xbf,  // [16384][1024] bf16
    const unsigned short* __restrict__ CT,   // [512][1024] bf16, n-major
    const float* __restrict__ D,
    const unsigned short* __restrict__ Ubf,  // [16384][512] bf16 (for D*u)
    float* __restrict__ Y)
{
    __shared__ unsigned short As[128 * 32];
    __shared__ unsigned short Bs[128 * 32];
    const int tid = threadIdx.x;
    const int w = tid >> 6, l = tid & 63;
    const int bm = blockIdx.x * 128;
    const int bn = blockIdx.y * 128;
    const int wm = (w & 1) * 64, wn = (w >> 1) * 64;
    const int lr = l & 31, lh = l >> 5;
    const int srow = w * 16 + (l >> 2);
    const int scol = (l & 3) * 8;

    floatx16 acc[2][2];
#pragma unroll
    for (int i = 0; i < 2; ++i)
#pragma unroll
        for (int j = 0; j < 2; ++j) acc[i][j] = (floatx16)0.f;

    for (int k0 = 0; k0 < 1024; k0 += 32) {
        gld_lds16(&Xbf[(size_t)(bm + srow) * 1024 + k0 + scol],      &As[srow * 32 + scol]);
        gld_lds16(&Xbf[(size_t)(bm + 64 + srow) * 1024 + k0 + scol], &As[(64 + srow) * 32 + scol]);
        gld_lds16(&CT[(size_t)(bn + srow) * 1024 + k0 + scol],       &Bs[srow * 32 + scol]);
        gld_lds16(&CT[(size_t)(bn + 64 + srow) * 1024 + k0 + scol],  &Bs[(64 + srow) * 32 + scol]);
        __syncthreads();

        bf16x8 af[2][2], bfr[2][2];
#pragma unroll
        for (int i = 0; i < 2; ++i)
#pragma unroll
            for (int s = 0; s < 2; ++s)
                af[i][s] = *(const bf16x8*)&As[(wm + 32 * i + lr) * 32 + s * 16 + lh * 8];
#pragma unroll
        for (int j = 0; j < 2; ++j)
#pragma unroll
            for (int s = 0; s < 2; ++s)
                bfr[j][s] = *(const bf16x8*)&Bs[(wn + 32 * j + lr) * 32 + s * 16 + lh * 8];
#pragma unroll
        for (int s = 0; s < 2; ++s)
#pragma unroll
            for (int i = 0; i < 2; ++i)
#pragma unroll
                for (int j = 0; j < 2; ++j)
                    acc[i][j] = __builtin_amdgcn_mfma_f32_32x32x16_bf16(af[i][s], bfr[j][s], acc[i][j], 0, 0, 0);
        __syncthreads();
    }

#pragma unroll
    for (int i = 0; i < 2; ++i)
#pragma unroll
        for (int j = 0; j < 2; ++j) {
            int col = bn + wn + 32 * j + lr;
            float dv = D[col];
#pragma unroll
            for (int g = 0; g < 4; ++g)
#pragma unroll
                for (int r = 0; r < 4; ++r) {
                    int row = bm + wm + 32 * i + r + 8 * g + 4 * lh;
                    size_t off = (size_t)row * NDIM + col;
                    Y[off] = acc[i][j][g * 4 + r] + dv * bf2f(Ubf[off]);
                }
        }
}

extern "C" void kernel_launch(void* const* d_in, const int* in_sizes, int n_in,
                              void* d_out, int out_size, void* d_ws, size_t ws_size,
                              hipStream_t stream)
{
    const float* u     = (const float*)d_in[0];
    const float* C_re  = (const float*)d_in[1];
    const float* C_im  = (const float*)d_in[2];
    const float* B_re  = (const float*)d_in[3];
    const float* B_im  = (const float*)d_in[4];
    const float* D     = (const float*)d_in[5];
    const float* nu    = (const float*)d_in[6];
    const float* theta = (const float*)d_in[7];
    const float* gamma = (const float*)d_in[8];
    float* y = (float*)d_out;

    // Workspace (54 MB): X 32MB | ubf 16MB | BT 1MB | CT 1MB | carry 2MB | pre 2MB
    unsigned short* X   = (unsigned short*)d_ws;
    unsigned short* ubf = X + (size_t)M_ROWS * 1024;
    unsigned short* BT  = ubf + (size_t)M_ROWS * 512;
    unsigned short* CT  = BT + (size_t)1024 * 512;
    float* carry = (float*)(CT + (size_t)512 * 1024);
    float* pre   = carry + (size_t)BATCH * NCHUNK * NDIM * 2;

    k_prep<<<4096 + 1024, 256, 0, stream>>>(u, B_re, B_im, C_re, C_im, gamma, ubf, BT, CT);
    k_gemm_in<<<dim3(M_ROWS / 128, 8), 256, 0, stream>>>(ubf, BT, X);
    k_scan_carries<<<BATCH * NCHUNK, 256, 0, stream>>>(X, nu, theta, carry);
    k_scan_chain<<<(BATCH * NDIM) / 256, 256, 0, stream>>>(carry, nu, theta, pre);
    k_scan_apply<<<BATCH * NCHUNK, 256, 0, stream>>>(X, nu, theta, pre);
    k_gemm_out<<<dim3(M_ROWS / 128, 4), 256, 0, stream>>>(X, CT, D, ubf, y);
}

// Round 7
// 179.062 us; speedup vs baseline: 1.0577x; 1.0577x over previous
//
#include <hip/hip_runtime.h>
#include <hip/hip_bf16.h>
#include <math.h>
#include <stdint.h>

// Problem constants (reference: BATCH=8, T=2048, N=512)
#define BATCH 8
#define T_LEN 2048
#define NDIM 512
#define M_ROWS (BATCH * T_LEN)   // 16384
#define CHUNK 32                 // scan chunk length
#define NCHUNK (T_LEN / CHUNK)   // 64

typedef __attribute__((ext_vector_type(8))) short bf16x8;
typedef __attribute__((ext_vector_type(4))) float floatx4;

__device__ __forceinline__ unsigned short f2bf(float f) {
    union { float f; unsigned u; } v; v.f = f;
    unsigned r = v.u + 0x7fff + ((v.u >> 16) & 1);   // RTNE
    return (unsigned short)(r >> 16);
}
__device__ __forceinline__ float bf2f(unsigned short h) {
    union { unsigned u; float f; } v; v.u = ((unsigned)h) << 16;
    return v.f;
}
__device__ __forceinline__ float bf2f_lo(unsigned u) {
    union { unsigned u; float f; } v; v.u = u << 16; return v.f;
}
__device__ __forceinline__ float bf2f_hi(unsigned u) {
    union { unsigned u; float f; } v; v.u = u & 0xffff0000u; return v.f;
}

// async global->LDS, 16 bytes per lane. LDS dest is wave-uniform base + lane*16
// (lane-order contiguous) — hence BK=32 k-contiguous rows (64 B), no padding.
__device__ __forceinline__ void gld_lds16(const unsigned short* g, unsigned short* l) {
    __builtin_amdgcn_global_load_lds(
        (const __attribute__((address_space(1))) unsigned int*)(uintptr_t)g,
        (__attribute__((address_space(3))) unsigned int*)(uintptr_t)l,
        16, 0, 0);
}

// ---------------- prep (merged): u->bf16  +  transpose/convert B,C ----------
// blocks [0,4096): cvt_u flat; blocks [4096,5120): transpose tiles.
__global__ __launch_bounds__(256) void k_prep(
    const float* __restrict__ u,
    const float* __restrict__ Bre, const float* __restrict__ Bim,
    const float* __restrict__ Cre, const float* __restrict__ Cim,
    const float* __restrict__ gamma,
    unsigned short* __restrict__ ubf,
    unsigned short* __restrict__ BT, unsigned short* __restrict__ CT)
{
    __shared__ unsigned short tile[32][33];
    const int blk = blockIdx.x;
    if (blk < 4096) {
        size_t i = ((size_t)blk * 256 + threadIdx.x) * 8;
        float4 a = *(const float4*)&u[i];
        float4 b = *(const float4*)&u[i + 4];
        ushort4 p0, p1;
        p0.x = f2bf(a.x); p0.y = f2bf(a.y); p0.z = f2bf(a.z); p0.w = f2bf(a.w);
        p1.x = f2bf(b.x); p1.y = f2bf(b.y); p1.z = f2bf(b.z); p1.w = f2bf(b.w);
        *(ushort4*)&ubf[i] = p0;
        *(ushort4*)&ubf[i + 4] = p1;
        return;
    }
    const int p = blk - 4096;
    const int z = p >> 8;                    // 0..3
    const int rem = p & 255;
    const int n0 = (rem & 15) * 32, k0 = (rem >> 4) * 32;
    const float* __restrict__ src = (z == 0) ? Bre : (z == 1) ? Bim : (z == 2) ? Cre : Cim;
    const int tx = threadIdx.x & 31, ty = threadIdx.x >> 5;   // ty 0..7

#pragma unroll
    for (int j = 0; j < 4; ++j) {
        int k = k0 + ty + j * 8;
        float s = (z < 2) ? gamma[k] : (z == 3 ? -1.f : 1.f);
        tile[ty + j * 8][tx] = f2bf(s * src[(size_t)k * NDIM + n0 + tx]);
    }
    __syncthreads();
#pragma unroll
    for (int j = 0; j < 4; ++j) {
        int n = n0 + ty + j * 8;
        unsigned short v = tile[tx][ty + j * 8];
        if (z == 0)      BT[(size_t)n * 512 + k0 + tx] = v;
        else if (z == 1) BT[(size_t)(512 + n) * 512 + k0 + tx] = v;
        else if (z == 2) CT[(size_t)n * 1024 + k0 + tx] = v;
        else             CT[(size_t)n * 1024 + 512 + k0 + tx] = v;
    }
}

// ---------------- GEMM-in: X[16384][1024] = ubf[16384][512] @ BT^T ----------
// m97 structure: 128x128 tile, BK=32, global_load_lds staging, 16x16x32 MFMA.
__global__ __launch_bounds__(256) void k_gemm_in(
    const unsigned short* __restrict__ A,    // [16384][512] bf16
    const unsigned short* __restrict__ BT,   // [1024][512] bf16, n-major
    unsigned short* __restrict__ X)          // [16384][1024] bf16 out
{
    __shared__ unsigned short As[128 * 32];
    __shared__ unsigned short Bs[128 * 32];
    const int tid = threadIdx.x;
    const int w = tid >> 6, l = tid & 63;
    const int bm = blockIdx.x * 128;
    const int bn = blockIdx.y * 128;
    const int wm = (w & 1) * 64, wn = (w >> 1) * 64;
    const int lm = l & 15, lq = l >> 4;
    const int srow = w * 16 + (l >> 2);
    const int scol = (l & 3) * 8;

    floatx4 acc[4][4];
#pragma unroll
    for (int i = 0; i < 4; ++i)
#pragma unroll
        for (int j = 0; j < 4; ++j) acc[i][j] = (floatx4)0.f;

    for (int k0 = 0; k0 < 512; k0 += 32) {
        gld_lds16(&A[(size_t)(bm + srow) * 512 + k0 + scol],      &As[srow * 32 + scol]);
        gld_lds16(&A[(size_t)(bm + 64 + srow) * 512 + k0 + scol], &As[(64 + srow) * 32 + scol]);
        gld_lds16(&BT[(size_t)(bn + srow) * 512 + k0 + scol],      &Bs[srow * 32 + scol]);
        gld_lds16(&BT[(size_t)(bn + 64 + srow) * 512 + k0 + scol], &Bs[(64 + srow) * 32 + scol]);
        __syncthreads();

        bf16x8 af[4], bfr[4];
#pragma unroll
        for (int i = 0; i < 4; ++i)
            af[i] = *(const bf16x8*)&As[(wm + i * 16 + lm) * 32 + lq * 8];
#pragma unroll
        for (int j = 0; j < 4; ++j)
            bfr[j] = *(const bf16x8*)&Bs[(wn + j * 16 + lm) * 32 + lq * 8];
#pragma unroll
        for (int i = 0; i < 4; ++i)
#pragma unroll
            for (int j = 0; j < 4; ++j)
                acc[i][j] = __builtin_amdgcn_mfma_f32_16x16x32_bf16(af[i], bfr[j], acc[i][j], 0, 0, 0);
        __syncthreads();
    }

    // C/D layout: col=lane&15, row=(lane>>4)*4+r
#pragma unroll
    for (int i = 0; i < 4; ++i)
#pragma unroll
        for (int j = 0; j < 4; ++j) {
            int col = bn + wn + j * 16 + lm;
#pragma unroll
            for (int r = 0; r < 4; ++r) {
                int row = bm + wm + i * 16 + lq * 4 + r;
                X[(size_t)row * 1024 + col] = f2bf(acc[i][j][r]);
            }
        }
}

// ---------------- Scan pass A: per-chunk carries (2 channels/thread) --------
__global__ __launch_bounds__(256) void k_scan_carries(
    const unsigned short* __restrict__ X,
    const float* __restrict__ nu, const float* __restrict__ theta,
    float* __restrict__ carry)   // [b][c][n] float2 interleaved
{
    const int n0 = 2 * threadIdx.x;
    const int b = blockIdx.x >> 6, c = blockIdx.x & 63;
    float r0 = __expf(-__expf(nu[n0]));
    float r1 = __expf(-__expf(nu[n0 + 1]));
    float lre0 = r0 * __cosf(theta[n0]),     lim0 = r0 * __sinf(theta[n0]);
    float lre1 = r1 * __cosf(theta[n0 + 1]), lim1 = r1 * __sinf(theta[n0 + 1]);
    size_t m = (size_t)b * T_LEN + (size_t)c * CHUNK;
    float xre0 = 0.f, xim0 = 0.f, xre1 = 0.f, xim1 = 0.f;
#pragma unroll 8
    for (int t = 0; t < CHUNK; ++t, ++m) {
        unsigned re = *(const unsigned*)&X[m * 1024 + n0];
        unsigned im = *(const unsigned*)&X[m * 1024 + 512 + n0];
        float u0 = bf2f_lo(re), u1 = bf2f_hi(re);
        float v0 = bf2f_lo(im), v1 = bf2f_hi(im);
        float a0 = lre0 * xre0 - lim0 * xim0 + u0;
        float b0 = lre0 * xim0 + lim0 * xre0 + v0;
        float a1 = lre1 * xre1 - lim1 * xim1 + u1;
        float b1 = lre1 * xim1 + lim1 * xre1 + v1;
        xre0 = a0; xim0 = b0; xre1 = a1; xim1 = b1;
    }
    size_t ci = ((size_t)b * NCHUNK + c) * NDIM + n0;
    *(float4*)&carry[ci * 2] = make_float4(xre0, xim0, xre1, xim1);
}

// ---------------- Scan pass B: chain carries across chunks ------------------
__global__ __launch_bounds__(256) void k_scan_chain(
    const float* __restrict__ carry,
    const float* __restrict__ nu, const float* __restrict__ theta,
    float* __restrict__ pre)     // exclusive prefix, float2 interleaved
{
    const int tid = blockIdx.x * blockDim.x + threadIdx.x;  // 0..4095
    const int b = tid >> 9, n = tid & (NDIM - 1);
    const float ex = __expf(nu[n]);
    const float rC = expf(-ex * (float)CHUNK);
    const float th = theta[n] * (float)CHUNK;
    const float a = rC * cosf(th);
    const float bb = rC * sinf(th);
    float Xre = 0.f, Xim = 0.f;
    for (int c = 0; c < NCHUNK; ++c) {
        size_t idx = ((size_t)b * NCHUNK + c) * NDIM + n;
        *(float2*)&pre[idx * 2] = make_float2(Xre, Xim);
        float2 cv = *(const float2*)&carry[idx * 2];
        float nre = a * Xre - bb * Xim + cv.x;
        float nim = a * Xim + bb * Xre + cv.y;
        Xre = nre; Xim = nim;
    }
}

// ---------------- Scan pass C: redo local scan from prefix, in place --------
__global__ __launch_bounds__(256) void k_scan_apply(
    unsigned short* __restrict__ X,
    const float* __restrict__ nu, const float* __restrict__ theta,
    const float* __restrict__ pre)
{
    const int n0 = 2 * threadIdx.x;
    const int b = blockIdx.x >> 6, c = blockIdx.x & 63;
    size_t pi = ((size_t)b * NCHUNK + c) * NDIM + n0;
    float4 P = *(const float4*)&pre[pi * 2];    // (re0, im0, re1, im1)
    float r0 = __expf(-__expf(nu[n0]));
    float r1 = __expf(-__expf(nu[n0 + 1]));
    float lre0 = r0 * __cosf(theta[n0]),     lim0 = r0 * __sinf(theta[n0]);
    float lre1 = r1 * __cosf(theta[n0 + 1]), lim1 = r1 * __sinf(theta[n0 + 1]);
    float xre0 = P.x, xim0 = P.y, xre1 = P.z, xim1 = P.w;
    size_t m = (size_t)b * T_LEN + (size_t)c * CHUNK;
#pragma unroll 8
    for (int t = 0; t < CHUNK; ++t, ++m) {
        unsigned re = *(const unsigned*)&X[m * 1024 + n0];
        unsigned im = *(const unsigned*)&X[m * 1024 + 512 + n0];
        float u0 = bf2f_lo(re), u1 = bf2f_hi(re);
        float v0 = bf2f_lo(im), v1 = bf2f_hi(im);
        float a0 = lre0 * xre0 - lim0 * xim0 + u0;
        float b0 = lre0 * xim0 + lim0 * xre0 + v0;
        float a1 = lre1 * xre1 - lim1 * xim1 + u1;
        float b1 = lre1 * xim1 + lim1 * xre1 + v1;
        xre0 = a0; xim0 = b0; xre1 = a1; xim1 = b1;
        unsigned pr = (unsigned)f2bf(xre0) | ((unsigned)f2bf(xre1) << 16);
        unsigned pim = (unsigned)f2bf(xim0) | ((unsigned)f2bf(xim1) << 16);
        *(unsigned*)&X[m * 1024 + n0] = pr;
        *(unsigned*)&X[m * 1024 + 512 + n0] = pim;
    }
}

// ---------------- GEMM-out: Y = X[16384][1024] @ CT^T + D*u -----------------
// 64x128 tile -> grid (256,4)=1024 blocks (~4 blocks/CU) for latency hiding.
__global__ __launch_bounds__(256) void k_gemm_out(
    const unsigned short* __restrict__ Xbf,  // [16384][1024] bf16
    const unsigned short* __restrict__ CT,   // [512][1024] bf16, n-major
    const float* __restrict__ D,
    const unsigned short* __restrict__ Ubf,  // [16384][512] bf16 (for D*u)
    float* __restrict__ Y)
{
    __shared__ unsigned short As[64 * 32];
    __shared__ unsigned short Bs[128 * 32];
    const int tid = threadIdx.x;
    const int w = tid >> 6, l = tid & 63;
    const int bm = blockIdx.x * 64;
    const int bn = blockIdx.y * 128;
    const int wm = (w & 1) * 32, wn = (w >> 1) * 64;  // wave tile 32x64
    const int lm = l & 15, lq = l >> 4;
    const int arow = tid >> 2;            // 0..63 (A staging: 4 lanes/row)
    const int acol = (tid & 3) * 8;
    const int srow = w * 16 + (l >> 2);   // 0..63 (B staging)
    const int scol = (l & 3) * 8;

    floatx4 acc[2][4];
#pragma unroll
    for (int i = 0; i < 2; ++i)
#pragma unroll
        for (int j = 0; j < 4; ++j) acc[i][j] = (floatx4)0.f;

    for (int k0 = 0; k0 < 1024; k0 += 32) {
        gld_lds16(&Xbf[(size_t)(bm + arow) * 1024 + k0 + acol],     &As[arow * 32 + acol]);
        gld_lds16(&CT[(size_t)(bn + srow) * 1024 + k0 + scol],      &Bs[srow * 32 + scol]);
        gld_lds16(&CT[(size_t)(bn + 64 + srow) * 1024 + k0 + scol], &Bs[(64 + srow) * 32 + scol]);
        __syncthreads();

        bf16x8 af[2], bfr[4];
#pragma unroll
        for (int i = 0; i < 2; ++i)
            af[i] = *(const bf16x8*)&As[(wm + i * 16 + lm) * 32 + lq * 8];
#pragma unroll
        for (int j = 0; j < 4; ++j)
            bfr[j] = *(const bf16x8*)&Bs[(wn + j * 16 + lm) * 32 + lq * 8];
#pragma unroll
        for (int i = 0; i < 2; ++i)
#pragma unroll
            for (int j = 0; j < 4; ++j)
                acc[i][j] = __builtin_amdgcn_mfma_f32_16x16x32_bf16(af[i], bfr[j], acc[i][j], 0, 0, 0);
        __syncthreads();
    }

#pragma unroll
    for (int i = 0; i < 2; ++i)
#pragma unroll
        for (int j = 0; j < 4; ++j) {
            int col = bn + wn + j * 16 + lm;
            float dv = D[col];
#pragma unroll
            for (int r = 0; r < 4; ++r) {
                int row = bm + wm + i * 16 + lq * 4 + r;
                size_t off = (size_t)row * NDIM + col;
                Y[off] = acc[i][j][r] + dv * bf2f(Ubf[off]);
            }
        }
}

extern "C" void kernel_launch(void* const* d_in, const int* in_sizes, int n_in,
                              void* d_out, int out_size, void* d_ws, size_t ws_size,
                              hipStream_t stream)
{
    const float* u     = (const float*)d_in[0];
    const float* C_re  = (const float*)d_in[1];
    const float* C_im  = (const float*)d_in[2];
    const float* B_re  = (const float*)d_in[3];
    const float* B_im  = (const float*)d_in[4];
    const float* D     = (const float*)d_in[5];
    const float* nu    = (const float*)d_in[6];
    const float* theta = (const float*)d_in[7];
    const float* gamma = (const float*)d_in[8];
    float* y = (float*)d_out;

    // Workspace (54 MB): X 32MB | ubf 16MB | BT 1MB | CT 1MB | carry 2MB | pre 2MB
    unsigned short* X   = (unsigned short*)d_ws;
    unsigned short* ubf = X + (size_t)M_ROWS * 1024;
    unsigned short* BT  = ubf + (size_t)M_ROWS * 512;
    unsigned short* CT  = BT + (size_t)1024 * 512;
    float* carry = (float*)(CT + (size_t)512 * 1024);
    float* pre   = carry + (size_t)BATCH * NCHUNK * NDIM * 2;

    k_prep<<<4096 + 1024, 256, 0, stream>>>(u, B_re, B_im, C_re, C_im, gamma, ubf, BT, CT);
    k_gemm_in<<<dim3(M_ROWS / 128, 8), 256, 0, stream>>>(ubf, BT, X);
    k_scan_carries<<<BATCH * NCHUNK, 256, 0, stream>>>(X, nu, theta, carry);
    k_scan_chain<<<(BATCH * NDIM) / 256, 256, 0, stream>>>(carry, nu, theta, pre);
    k_scan_apply<<<BATCH * NCHUNK, 256, 0, stream>>>(X, nu, theta, pre);
    k_gemm_out<<<dim3(M_ROWS / 64, 4), 256, 0, stream>>>(X, CT, D, ubf, y);
}

// Round 8
// 177.775 us; speedup vs baseline: 1.0654x; 1.0072x over previous
//
#include <hip/hip_runtime.h>
#include <hip/hip_bf16.h>
#include <math.h>
#include <stdint.h>

// Problem constants (reference: BATCH=8, T=2048, N=512)
#define BATCH 8
#define T_LEN 2048
#define NDIM 512
#define M_ROWS (BATCH * T_LEN)   // 16384
#define CHUNK 32                 // scan chunk length
#define NCHUNK (T_LEN / CHUNK)   // 64

// X layout is channel-interleaved: X[m][2n+0]=re_n, X[m][2n+1]=im_n.
// BT/CT rows are permuted to match (GEMM is K/N-permutation invariant).

typedef __attribute__((ext_vector_type(8))) short bf16x8;
typedef __attribute__((ext_vector_type(4))) float floatx4;

__device__ __forceinline__ unsigned short f2bf(float f) {
    union { float f; unsigned u; } v; v.f = f;
    unsigned r = v.u + 0x7fff + ((v.u >> 16) & 1);   // RTNE
    return (unsigned short)(r >> 16);
}
__device__ __forceinline__ float bf2f(unsigned short h) {
    union { unsigned u; float f; } v; v.u = ((unsigned)h) << 16;
    return v.f;
}
__device__ __forceinline__ float bf2f_lo(unsigned u) {
    union { unsigned u; float f; } v; v.u = u << 16; return v.f;
}
__device__ __forceinline__ float bf2f_hi(unsigned u) {
    union { unsigned u; float f; } v; v.u = u & 0xffff0000u; return v.f;
}

// async global->LDS, 16 bytes per lane. LDS dest is wave-uniform base + lane*16
// (lane-order contiguous) — hence BK=32 k-contiguous rows (64 B), no padding.
__device__ __forceinline__ void gld_lds16(const unsigned short* g, unsigned short* l) {
    __builtin_amdgcn_global_load_lds(
        (const __attribute__((address_space(1))) unsigned int*)(uintptr_t)g,
        (__attribute__((address_space(3))) unsigned int*)(uintptr_t)l,
        16, 0, 0);
}

// ---------------- prep (merged): u->bf16  +  transpose/convert B,C ----------
// blocks [0,4096): cvt_u flat; blocks [4096,5120): transpose tiles.
// BT[2n+p][k] = bf16(gamma[k]*B{re,im}[k][n])           (rows interleaved)
// CT[j][2n+p] = bf16(+Cre[n][j] / -Cim[n][j])           (cols interleaved)
__global__ __launch_bounds__(256) void k_prep(
    const float* __restrict__ u,
    const float* __restrict__ Bre, const float* __restrict__ Bim,
    const float* __restrict__ Cre, const float* __restrict__ Cim,
    const float* __restrict__ gamma,
    unsigned short* __restrict__ ubf,
    unsigned short* __restrict__ BT, unsigned short* __restrict__ CT)
{
    __shared__ unsigned short tile[32][33];
    const int blk = blockIdx.x;
    if (blk < 4096) {
        size_t i = ((size_t)blk * 256 + threadIdx.x) * 8;
        float4 a = *(const float4*)&u[i];
        float4 b = *(const float4*)&u[i + 4];
        ushort4 p0, p1;
        p0.x = f2bf(a.x); p0.y = f2bf(a.y); p0.z = f2bf(a.z); p0.w = f2bf(a.w);
        p1.x = f2bf(b.x); p1.y = f2bf(b.y); p1.z = f2bf(b.z); p1.w = f2bf(b.w);
        *(ushort4*)&ubf[i] = p0;
        *(ushort4*)&ubf[i + 4] = p1;
        return;
    }
    const int p = blk - 4096;
    const int z = p >> 8;                    // 0..3
    const int rem = p & 255;
    const int n0 = (rem & 15) * 32, k0 = (rem >> 4) * 32;
    const float* __restrict__ src = (z == 0) ? Bre : (z == 1) ? Bim : (z == 2) ? Cre : Cim;
    const int tx = threadIdx.x & 31, ty = threadIdx.x >> 5;   // ty 0..7

#pragma unroll
    for (int j = 0; j < 4; ++j) {
        int k = k0 + ty + j * 8;
        float s = (z < 2) ? gamma[k] : (z == 3 ? -1.f : 1.f);
        tile[ty + j * 8][tx] = f2bf(s * src[(size_t)k * NDIM + n0 + tx]);
    }
    __syncthreads();
#pragma unroll
    for (int j = 0; j < 4; ++j) {
        int n = n0 + ty + j * 8;
        unsigned short v = tile[tx][ty + j * 8];
        if (z < 2)   BT[(size_t)(2 * n + z) * 512 + k0 + tx] = v;          // row 2n+p
        else         CT[(size_t)n * 1024 + 2 * (k0 + tx) + (z - 2)] = v;   // col 2k+p
    }
}

// ---------------- GEMM-in + local scan + carries ----------------------------
// 128x128 tile, BK=32, global_load_lds, 16x16x32 MFMA. Tile = 64 complete
// channels x 4 complete T-chunks -> fused chunk-local recurrence in LDS.
#define XS_STRIDE 136   // shorts; 272 B = 17*16 (16B-aligned rows, bank-clean)
__global__ __launch_bounds__(256) void k_gemm_in_scan(
    const unsigned short* __restrict__ A,    // [16384][512] bf16
    const unsigned short* __restrict__ BT,   // [1024][512] bf16 (interleaved rows)
    const float* __restrict__ nu, const float* __restrict__ theta,
    unsigned short* __restrict__ X,          // [16384][1024] bf16, interleaved
    float* __restrict__ carry)               // [b][c][n] float2
{
    __shared__ __align__(16) unsigned short smem[128 * XS_STRIDE]; // 34816 B
    unsigned short* As = smem;               // 8192 B during K-loop
    unsigned short* Bs = smem + 4096;        // 8192 B during K-loop
    unsigned short* Xs = smem;               // 128 x XS_STRIDE after K-loop

    const int tid = threadIdx.x;
    const int w = tid >> 6, l = tid & 63;
    const int bm = blockIdx.x * 128;
    const int bn = blockIdx.y * 128;
    const int wm = (w & 1) * 64, wn = (w >> 1) * 64;
    const int lm = l & 15, lq = l >> 4;
    const int srow = w * 16 + (l >> 2);
    const int scol = (l & 3) * 8;

    floatx4 acc[4][4];
#pragma unroll
    for (int i = 0; i < 4; ++i)
#pragma unroll
        for (int j = 0; j < 4; ++j) acc[i][j] = (floatx4)0.f;

    for (int k0 = 0; k0 < 512; k0 += 32) {
        gld_lds16(&A[(size_t)(bm + srow) * 512 + k0 + scol],      &As[srow * 32 + scol]);
        gld_lds16(&A[(size_t)(bm + 64 + srow) * 512 + k0 + scol], &As[(64 + srow) * 32 + scol]);
        gld_lds16(&BT[(size_t)(bn + srow) * 512 + k0 + scol],      &Bs[srow * 32 + scol]);
        gld_lds16(&BT[(size_t)(bn + 64 + srow) * 512 + k0 + scol], &Bs[(64 + srow) * 32 + scol]);
        __syncthreads();

        bf16x8 af[4], bfr[4];
#pragma unroll
        for (int i = 0; i < 4; ++i)
            af[i] = *(const bf16x8*)&As[(wm + i * 16 + lm) * 32 + lq * 8];
#pragma unroll
        for (int j = 0; j < 4; ++j)
            bfr[j] = *(const bf16x8*)&Bs[(wn + j * 16 + lm) * 32 + lq * 8];
#pragma unroll
        for (int i = 0; i < 4; ++i)
#pragma unroll
            for (int j = 0; j < 4; ++j)
                acc[i][j] = __builtin_amdgcn_mfma_f32_16x16x32_bf16(af[i], bfr[j], acc[i][j], 0, 0, 0);
        __syncthreads();
    }

    // phase 1: acc -> Xs (bf16). C/D layout: col=lane&15, row=(lane>>4)*4+r.
#pragma unroll
    for (int i = 0; i < 4; ++i)
#pragma unroll
        for (int j = 0; j < 4; ++j) {
            int col = wn + j * 16 + lm;
#pragma unroll
            for (int r = 0; r < 4; ++r) {
                int row = wm + i * 16 + lq * 4 + r;
                Xs[row * XS_STRIDE + col] = f2bf(acc[i][j][r]);
            }
        }
    __syncthreads();

    // phase 2: chunk-local complex recurrence in LDS (in place) + carry out.
    {
        const int cc = tid >> 6;                 // chunk within tile 0..3
        const int ch = tid & 63;                 // channel within tile 0..63
        const int n  = (bn >> 1) + ch;           // global channel
        const int b  = bm >> 11;
        const int c  = ((bm & 2047) >> 5) + cc;  // global chunk 0..63
        const float rr  = __expf(-__expf(nu[n]));
        const float lre = rr * __cosf(theta[n]);
        const float lim = rr * __sinf(theta[n]);
        float xre = 0.f, xim = 0.f;
        int base = (cc * 32) * XS_STRIDE + 2 * ch;
#pragma unroll 8
        for (int t = 0; t < 32; ++t) {
            unsigned v = *(const unsigned*)&Xs[base + t * XS_STRIDE];
            float nre = lre * xre - lim * xim + bf2f_lo(v);
            float nim = lre * xim + lim * xre + bf2f_hi(v);
            xre = nre; xim = nim;
            *(unsigned*)&Xs[base + t * XS_STRIDE] =
                (unsigned)f2bf(xre) | ((unsigned)f2bf(xim) << 16);
        }
        size_t ci = ((size_t)b * NCHUNK + c) * NDIM + n;
        *(float2*)&carry[ci * 2] = make_float2(xre, xim);
    }
    __syncthreads();

    // phase 3: coalesced X write (16 lanes x 16B = 256B contiguous per row).
#pragma unroll
    for (int it = 0; it < 8; ++it) {
        int row = (tid >> 4) + 16 * it;
        int cs  = (tid & 15) * 8;
        uint4 v = *(const uint4*)&Xs[row * XS_STRIDE + cs];
        *(uint4*)&X[(size_t)(bm + row) * 1024 + bn + cs] = v;
    }
}

// ---------------- chain carries across chunks (exclusive prefix) ------------
__global__ __launch_bounds__(256) void k_scan_chain(
    const float* __restrict__ carry,
    const float* __restrict__ nu, const float* __restrict__ theta,
    float* __restrict__ pre)
{
    const int tid = blockIdx.x * blockDim.x + threadIdx.x;  // 0..4095
    const int b = tid >> 9, n = tid & (NDIM - 1);
    const float ex = __expf(nu[n]);
    const float rC = expf(-ex * (float)CHUNK);
    const float th = theta[n] * (float)CHUNK;
    const float a = rC * cosf(th);
    const float bb = rC * sinf(th);
    float Xre = 0.f, Xim = 0.f;
    for (int c = 0; c < NCHUNK; ++c) {
        size_t idx = ((size_t)b * NCHUNK + c) * NDIM + n;
        *(float2*)&pre[idx * 2] = make_float2(Xre, Xim);
        float2 cv = *(const float2*)&carry[idx * 2];
        float nre = a * Xre - bb * Xim + cv.x;
        float nim = a * Xim + bb * Xre + cv.y;
        Xre = nre; Xim = nim;
    }
}

// ---------------- apply: correction-only, X += lam^{t+1} * P ----------------
// X holds chunk-local scans; add the chained prefix. c==0 blocks are no-ops.
__global__ __launch_bounds__(256) void k_scan_apply(
    unsigned short* __restrict__ X,
    const float* __restrict__ nu, const float* __restrict__ theta,
    const float* __restrict__ pre)
{
    const int b = blockIdx.x >> 6, c = blockIdx.x & 63;
    if (c == 0) return;
    const int t2 = threadIdx.x;              // channels 2*t2, 2*t2+1
    const int n0 = 2 * t2;
    size_t pi = ((size_t)b * NCHUNK + c) * NDIM + n0;
    float4 P = *(const float4*)&pre[pi * 2];   // (re0,im0,re1,im1)
    float r0 = __expf(-__expf(nu[n0]));
    float r1 = __expf(-__expf(nu[n0 + 1]));
    float lre0 = r0 * __cosf(theta[n0]),     lim0 = r0 * __sinf(theta[n0]);
    float lre1 = r1 * __cosf(theta[n0 + 1]), lim1 = r1 * __sinf(theta[n0 + 1]);
    float fre0 = lre0, fim0 = lim0, fre1 = lre1, fim1 = lim1;   // lam^{t+1}
    size_t m = (size_t)b * T_LEN + (size_t)c * CHUNK;
#pragma unroll 8
    for (int t = 0; t < CHUNK; ++t, ++m) {
        uint2 v = *(const uint2*)&X[m * 1024 + n0 * 2];
        float xre0 = bf2f_lo(v.x) + (fre0 * P.x - fim0 * P.y);
        float xim0 = bf2f_hi(v.x) + (fre0 * P.y + fim0 * P.x);
        float xre1 = bf2f_lo(v.y) + (fre1 * P.z - fim1 * P.w);
        float xim1 = bf2f_hi(v.y) + (fre1 * P.w + fim1 * P.z);
        uint2 o;
        o.x = (unsigned)f2bf(xre0) | ((unsigned)f2bf(xim0) << 16);
        o.y = (unsigned)f2bf(xre1) | ((unsigned)f2bf(xim1) << 16);
        *(uint2*)&X[m * 1024 + n0 * 2] = o;
        float a0 = fre0 * lre0 - fim0 * lim0, b0 = fre0 * lim0 + fim0 * lre0;
        float a1 = fre1 * lre1 - fim1 * lim1, b1 = fre1 * lim1 + fim1 * lre1;
        fre0 = a0; fim0 = b0; fre1 = a1; fim1 = b1;
    }
}

// ---------------- GEMM-out: Y = X @ CT^T + D*u ------------------------------
// 64x128 tile, LDS-repacked fp32 epilogue for coalesced Y stores / Ubf loads.
#define YS_STRIDE 132   // floats; 528 B = 33*16
__global__ __launch_bounds__(256) void k_gemm_out(
    const unsigned short* __restrict__ Xbf,  // [16384][1024] bf16 interleaved
    const unsigned short* __restrict__ CT,   // [512][1024] bf16 interleaved cols
    const float* __restrict__ D,
    const unsigned short* __restrict__ Ubf,  // [16384][512] bf16 (for D*u)
    float* __restrict__ Y)
{
    __shared__ __align__(16) char smem[64 * YS_STRIDE * 4];  // 33792 B
    unsigned short* As = (unsigned short*)smem;              // 4096 B
    unsigned short* Bs = (unsigned short*)(smem + 4096);     // 8192 B
    float* Ys = (float*)smem;                                // 64 x YS_STRIDE

    const int tid = threadIdx.x;
    const int w = tid >> 6, l = tid & 63;
    const int bm = blockIdx.x * 64;
    const int bn = blockIdx.y * 128;
    const int wm = (w & 1) * 32, wn = (w >> 1) * 64;  // wave tile 32x64
    const int lm = l & 15, lq = l >> 4;
    const int arow = tid >> 2;            // 0..63 (A staging)
    const int acol = (tid & 3) * 8;
    const int srow = w * 16 + (l >> 2);   // 0..63 (B staging)
    const int scol = (l & 3) * 8;

    floatx4 acc[2][4];
#pragma unroll
    for (int i = 0; i < 2; ++i)
#pragma unroll
        for (int j = 0; j < 4; ++j) acc[i][j] = (floatx4)0.f;

    for (int k0 = 0; k0 < 1024; k0 += 32) {
        gld_lds16(&Xbf[(size_t)(bm + arow) * 1024 + k0 + acol],     &As[arow * 32 + acol]);
        gld_lds16(&CT[(size_t)(bn + srow) * 1024 + k0 + scol],      &Bs[srow * 32 + scol]);
        gld_lds16(&CT[(size_t)(bn + 64 + srow) * 1024 + k0 + scol], &Bs[(64 + srow) * 32 + scol]);
        __syncthreads();

        bf16x8 af[2], bfr[4];
#pragma unroll
        for (int i = 0; i < 2; ++i)
            af[i] = *(const bf16x8*)&As[(wm + i * 16 + lm) * 32 + lq * 8];
#pragma unroll
        for (int j = 0; j < 4; ++j)
            bfr[j] = *(const bf16x8*)&Bs[(wn + j * 16 + lm) * 32 + lq * 8];
#pragma unroll
        for (int i = 0; i < 2; ++i)
#pragma unroll
            for (int j = 0; j < 4; ++j)
                acc[i][j] = __builtin_amdgcn_mfma_f32_16x16x32_bf16(af[i], bfr[j], acc[i][j], 0, 0, 0);
        __syncthreads();
    }

    // phase 1: acc -> Ys (fp32)
#pragma unroll
    for (int i = 0; i < 2; ++i)
#pragma unroll
        for (int j = 0; j < 4; ++j) {
            int col = wn + j * 16 + lm;
#pragma unroll
            for (int r = 0; r < 4; ++r) {
                int row = wm + i * 16 + lq * 4 + r;
                Ys[row * YS_STRIDE + col] = acc[i][j][r];
            }
        }
    __syncthreads();

    // phase 2: coalesced epilogue (32 lanes x 16B = 512B contiguous per row)
#pragma unroll
    for (int it = 0; it < 8; ++it) {
        int row = (tid >> 5) + 8 * it;
        int cs  = (tid & 31) * 4;
        float4 a = *(const float4*)&Ys[row * YS_STRIDE + cs];
        float4 d = *(const float4*)&D[bn + cs];
        uint2 uv = *(const uint2*)&Ubf[(size_t)(bm + row) * 512 + bn + cs];
        float4 o;
        o.x = a.x + d.x * bf2f_lo(uv.x);
        o.y = a.y + d.y * bf2f_hi(uv.x);
        o.z = a.z + d.z * bf2f_lo(uv.y);
        o.w = a.w + d.w * bf2f_hi(uv.y);
        *(float4*)&Y[(size_t)(bm + row) * 512 + bn + cs] = o;
    }
}

extern "C" void kernel_launch(void* const* d_in, const int* in_sizes, int n_in,
                              void* d_out, int out_size, void* d_ws, size_t ws_size,
                              hipStream_t stream)
{
    const float* u     = (const float*)d_in[0];
    const float* C_re  = (const float*)d_in[1];
    const float* C_im  = (const float*)d_in[2];
    const float* B_re  = (const float*)d_in[3];
    const float* B_im  = (const float*)d_in[4];
    const float* D     = (const float*)d_in[5];
    const float* nu    = (const float*)d_in[6];
    const float* theta = (const float*)d_in[7];
    const float* gamma = (const float*)d_in[8];
    float* y = (float*)d_out;

    // Workspace (54 MB): X 32MB | ubf 16MB | BT 1MB | CT 1MB | carry 2MB | pre 2MB
    unsigned short* X   = (unsigned short*)d_ws;
    unsigned short* ubf = X + (size_t)M_ROWS * 1024;
    unsigned short* BT  = ubf + (size_t)M_ROWS * 512;
    unsigned short* CT  = BT + (size_t)1024 * 512;
    float* carry = (float*)(CT + (size_t)512 * 1024);
    float* pre   = carry + (size_t)BATCH * NCHUNK * NDIM * 2;

    k_prep<<<4096 + 1024, 256, 0, stream>>>(u, B_re, B_im, C_re, C_im, gamma, ubf, BT, CT);
    k_gemm_in_scan<<<dim3(M_ROWS / 128, 8), 256, 0, stream>>>(ubf, BT, nu, theta, X, carry);
    k_scan_chain<<<(BATCH * NDIM) / 256, 256, 0, stream>>>(carry, nu, theta, pre);
    k_scan_apply<<<BATCH * NCHUNK, 256, 0, stream>>>(X, nu, theta, pre);
    k_gemm_out<<<dim3(M_ROWS / 64, 4), 256, 0, stream>>>(X, CT, D, ubf, y);
}